// Round 12
// baseline (262.274 us; speedup 1.0000x reference)
//
#include <hip/hip_runtime.h>

#define NHEADS 12
#define SEQ    1024
#define HDIM   768
#define DHEAD  64
#define BH_TOT 48
#define EPSN   1e-6f

typedef __attribute__((ext_vector_type(8))) short    bf8;  // 8 bf16 (4 VGPRs) MFMA A/B frag
typedef __attribute__((ext_vector_type(4))) float    fx4;  // MFMA C/D frag / float4
typedef __attribute__((ext_vector_type(4))) _Float16 h4;   // 4 f16 (2 VGPRs) 16x16x16 frag
typedef __attribute__((ext_vector_type(2))) unsigned int u32x2;

#define SZT 3145728u   // 48*1024*64 elements (one head-split tensor)
#define WSZ 589824u    // 768*768 elements (one weight matrix)

__device__ __forceinline__ float bf2f(unsigned short h) {
  union { unsigned int u; float f; } v; v.u = ((unsigned int)h) << 16; return v.f;
}
__device__ __forceinline__ unsigned short f2bf(float f) {
  union { float f; unsigned int u; } v; v.f = f;
  unsigned int u = v.u;
  return (unsigned short)((u + 0x7FFFu + ((u >> 16) & 1u)) >> 16);
}

// Cross-quad max (lane ^16 then ^32) via gfx950 permlane*_swap: VALU ops
// (~4cyc) replacing ds_swizzle (~120cyc LDS-pipe latency) on the softmax
// critical path. swap(x,x) returns (a',b') with per-lane fmax(a',b') =
// max(x[lane], x[lane^K]) -- bit-identical to the __shfl_xor butterfly.
__device__ __forceinline__ float crossmax(float x) {
#if __has_builtin(__builtin_amdgcn_permlane16_swap) && __has_builtin(__builtin_amdgcn_permlane32_swap)
  u32x2 r = __builtin_amdgcn_permlane16_swap(__float_as_uint(x), __float_as_uint(x), false, false);
  x = fmaxf(__uint_as_float(r.x), __uint_as_float(r.y));
  r = __builtin_amdgcn_permlane32_swap(__float_as_uint(x), __float_as_uint(x), false, false);
  x = fmaxf(__uint_as_float(r.x), __uint_as_float(r.y));
#else
  x = fmaxf(x, __shfl_xor(x, 16));
  x = fmaxf(x, __shfl_xor(x, 32));
#endif
  return x;
}

// async global->LDS, 16B per lane; LDS dest = wave-uniform base + lane*16.
typedef __attribute__((address_space(3))) unsigned int lds_u32;
typedef __attribute__((address_space(1))) const unsigned int glb_u32;
__device__ __forceinline__ void gld16(const unsigned short* g, unsigned short* l) {
  __builtin_amdgcn_global_load_lds((glb_u32*)g, (lds_u32*)l, 16, 0, 0);
}

// ---------------------------------------------------------------------------
// One-shot f32 -> bf16 conversion of X (hs,te,se) and W (q,k,v,t,s) into ws.
// Layout (ushort units): hsb@5SZ teb@6SZ seb@7SZ  W[z]@8SZ + z*WSZ
// ---------------------------------------------------------------------------
__global__ void convert_kernel(const float* __restrict__ hs, const float* __restrict__ te,
                               const float* __restrict__ se,
                               const float* __restrict__ Wq, const float* __restrict__ Wk,
                               const float* __restrict__ Wv, const float* __restrict__ Wt,
                               const float* __restrict__ Ws2,
                               unsigned short* __restrict__ ws)
{
  const int z = blockIdx.y;
  const float* src;
  unsigned short* dst;
  int n;
  if (z < 3) {
    src = (z == 0) ? hs : (z == 1) ? te : se;
    dst = ws + (size_t)(5 + z) * SZT;
    n = 3145728;
  } else {
    src = (z == 3) ? Wq : (z == 4) ? Wk : (z == 5) ? Wv : (z == 6) ? Wt : Ws2;
    dst = ws + (size_t)8 * SZT + (size_t)(z - 3) * WSZ;
    n = 589824;
  }
  const int base = (blockIdx.x * 256 + threadIdx.x) * 8;
  if (base >= n) return;
  const fx4 a = *(const fx4*)(src + base);
  const fx4 b = *(const fx4*)(src + base + 4);
  bf8 o;
#pragma unroll
  for (int j = 0; j < 4; ++j) { o[j] = (short)f2bf(a[j]); o[4 + j] = (short)f2bf(b[j]); }
  *(bf8*)(dst + base) = o;
}

// ---------------------------------------------------------------------------
// Projection GEMM (bf16 in): out = X[4096,768] @ W[768,768]^T + b, head-split.
// XCD-aware 1-D grid 960 (r8). xcd = lin&7 owns y-tiles xcd*4..xcd*4+3 for
// ALL x and z -> same-XCD blocks share X panels (784KB, L2-resident) + W
// panels. z: 0=Q 1=K 2=V(f16, transposed Vt[bh*64+d][1024]) 3=T 4=S
// ---------------------------------------------------------------------------
__global__ __launch_bounds__(256, 3)
void proj_kernel(unsigned short* __restrict__ ws,
                 const float* __restrict__ bq, const float* __restrict__ bk,
                 const float* __restrict__ bv, const float* __restrict__ bt,
                 const float* __restrict__ bs)
{
  __shared__ unsigned short Xs[2][4096];
  __shared__ unsigned short Ys[2][4096];

  // Decode XCD-grouped tile assignment from 1-D block id.
  const int lin = blockIdx.x;          // 0..959
  const int xcd = lin & 7;
  const int idx = lin >> 3;            // 0..119
  const int xt  = idx % 6;             // N-tile
  const int t2  = idx / 6;             // 0..19
  const int yl  = t2 % 4;
  const int z   = t2 / 4;              // 0..4
  const int yt  = xcd * 4 + yl;        // M-tile, grouped per XCD

  const unsigned short* X = ws + (size_t)5 * SZT + (size_t)((z < 3) ? 0 : (z - 2)) * SZT;
  const unsigned short* W = ws + (size_t)8 * SZT + (size_t)z * WSZ;
  const float* bias = (z == 0) ? bq : (z == 1) ? bk : (z == 2) ? bv : (z == 3) ? bt : bs;
  unsigned short* out = ws + (size_t)((z < 2) ? z : (z == 2) ? 4 : (z == 3) ? 2 : 3) * SZT;

  const int tid   = threadIdx.x;
  const int lane  = tid & 63;
  const int wid   = tid >> 6;
  const int wm    = wid >> 1, wn = wid & 1;
  const int colid = lane & 15, quad = lane >> 4;
  const int m0 = yt * 128, n0 = xt * 128;

  auto stage = [&](int kt, int pb) {
#pragma unroll
    for (int i = 0; i < 2; ++i) {
      const int slot = i * 256 + tid;        // 0..511, 16B each
      const int row = slot >> 2, ch = slot & 3;
      gld16(X + (m0 + row) * HDIM + kt + ch * 8, &Xs[pb][slot * 8]);
      gld16(W + (n0 + row) * HDIM + kt + ch * 8, &Ys[pb][slot * 8]);
    }
  };

  fx4 acc[4][4];
#pragma unroll
  for (int i = 0; i < 4; ++i)
#pragma unroll
    for (int j = 0; j < 4; ++j) acc[i][j] = (fx4){0.f, 0.f, 0.f, 0.f};

  stage(0, 0);
  __syncthreads();

  for (int it = 0; it < 24; ++it) {
    const int pb = it & 1;
    if (it + 1 < 24) stage((it + 1) * 32, pb ^ 1);

    bf8 af[4], bfr[4];
#pragma unroll
    for (int i = 0; i < 4; ++i)
      af[i] = *(const bf8*)&Xs[pb][(wm * 64 + i * 16 + colid) * 32 + quad * 8];
#pragma unroll
    for (int j = 0; j < 4; ++j)
      bfr[j] = *(const bf8*)&Ys[pb][(wn * 64 + j * 16 + colid) * 32 + quad * 8];
#pragma unroll
    for (int i = 0; i < 4; ++i)
#pragma unroll
      for (int j = 0; j < 4; ++j)
        acc[i][j] = __builtin_amdgcn_mfma_f32_16x16x32_bf16(af[i], bfr[j], acc[i][j], 0, 0, 0);
    __syncthreads();
  }

  // Epilogue. C/D layout: col=lane&15, row=quad*4+reg.
  if (z != 2) {
#pragma unroll
    for (int i = 0; i < 4; ++i) {
      const int r0 = m0 + wm * 64 + i * 16 + quad * 4;
      const int bb = r0 >> 10, s0 = r0 & 1023;
#pragma unroll
      for (int j = 0; j < 4; ++j) {
        const int c = n0 + wn * 64 + j * 16 + colid;
        const int h = c >> 6, d = c & 63;
        const float bvl = bias[c];
        unsigned short* op = out + (((bb * NHEADS + h) * SEQ + s0) * DHEAD + d);
#pragma unroll
        for (int reg = 0; reg < 4; ++reg)
          op[reg * DHEAD] = f2bf(acc[i][j][reg] + bvl);
      }
    }
  } else {
    // V -> f16, transposed: Vt[(bh*64+d)*1024 + s], 4 consecutive s per 8B store.
#pragma unroll
    for (int i = 0; i < 4; ++i) {
      const int r0 = m0 + wm * 64 + i * 16 + quad * 4;
      const int bb = r0 >> 10, s0 = r0 & 1023;
#pragma unroll
      for (int j = 0; j < 4; ++j) {
        const int c = n0 + wn * 64 + j * 16 + colid;
        const int h = c >> 6, d = c & 63;
        const float bvl = bias[c];
        h4 pk;
#pragma unroll
        for (int reg = 0; reg < 4; ++reg)
          pk[reg] = (_Float16)(acc[i][j][reg] + bvl);
        *(h4*)(void*)(out + ((size_t)((bb * NHEADS + h) * DHEAD + d)) * SEQ + s0) = pk;
      }
    }
  }
}

// ---------------------------------------------------------------------------
// Flash attention. Round 18: r11 (52.8us) + ONE change: merge the two 32-key
// halves into one 64-key softmax per (tile, q-group). The hh split was a
// register-pressure artifact (VGPR 128 of 256 budget); merging loads all 4
// ff frags up front (+~56 VGPR) and runs per g: 12 QK MFMAs -> sv[4][4] ->
// ONE 15-fmax tree -> ONE crossmax -> ONE defer-branch -> 16-wide exp batch
// (2x TRANS ILP) -> 16 PV MFMAs. Halves per-tile crossmax/branch/rescale
// count; ff accumulation order unchanged (ulp-equivalent). AI, occupancy,
// staging, swizzle all byte-identical.
// Proven stack: r3 structure + defer-max (r9) + deferred-l (r10) +
// permlane crossmax (r11) + XCD-grouped grids (r8).
// LAWS: (1) q/wave >= 32; (2) don't buy occupancy with VGPR caps or AI;
// (3) no scheduler-fencing intrinsics in the inner loop; (4) one change
// per round.
// ---------------------------------------------------------------------------
__global__ __launch_bounds__(256, 2)
void attn_kernel(const unsigned short* __restrict__ ws,
                 const float* __restrict__ maskb,
                 float* __restrict__ outb)
{
  const unsigned short* Qb  = ws;
  const unsigned short* GT0 = ws + (size_t)1 * SZT;   // K
  const unsigned short* GT1 = ws + (size_t)2 * SZT;   // T
  const unsigned short* GT2 = ws + (size_t)3 * SZT;   // S
  const unsigned short* Vtu = ws + (size_t)4 * SZT;   // V f16 transposed, as ushort

  __shared__ unsigned short Ls[2][4][64][64];  // 64 KB: [buf][K,T,S,V][row][col]

  const int tid   = threadIdx.x;
  const int lane  = tid & 63;
  const int wid   = tid >> 6;          // 0..3
  const int colid = lane & 15, quad = lane >> 4;

  // XCD swizzle: 384 blocks; lin&7 = XCD; each XCD owns 6 bh entirely.
  const int lin = blockIdx.x;
  const int xcd = lin & 7;
  const int idx = lin >> 3;            // 0..47
  const int bh  = xcd * 6 + (idx % 6);
  const int qx  = idx / 6;             // 0..7
  const int b   = bh / NHEADS, h = bh % NHEADS;
  const int q0  = qx * 128 + wid * 32;
  const int base_h = bh * SEQ * DHEAD;

  // Query-side B-frags for 2 q-groups: lane holds B[k=quad*8+j][n=colid].
  bf8 bqf[2][2], btf[2][2], bsf[2][2];
  float rs[2];
#pragma unroll
  for (int g = 0; g < 2; ++g) {
    const int row = q0 + g * 16 + colid;
    const unsigned short* qp = Qb  + base_h + row * 64 + quad * 8;
    const unsigned short* tp = GT1 + base_h + row * 64 + quad * 8;
    const unsigned short* sp = GT2 + base_h + row * 64 + quad * 8;
    bqf[g][0] = *(const bf8*)qp;  bqf[g][1] = *(const bf8*)(qp + 32);
    btf[g][0] = *(const bf8*)tp;  btf[g][1] = *(const bf8*)(tp + 32);
    bsf[g][0] = *(const bf8*)sp;  bsf[g][1] = *(const bf8*)(sp + 32);
    float t2 = 0.f, s2 = 0.f;
#pragma unroll
    for (int fr = 0; fr < 2; ++fr)
#pragma unroll
      for (int j = 0; j < 8; ++j) {
        const float tv = bf2f((unsigned short)btf[g][fr][j]);
        const float sv2 = bf2f((unsigned short)bsf[g][fr][j]);
        t2 += tv * tv; s2 += sv2 * sv2;
      }
    t2 += __shfl_xor(t2, 16); t2 += __shfl_xor(t2, 32);
    s2 += __shfl_xor(s2, 16); s2 += __shfl_xor(s2, 32);
    rs[g] = 1.0f / ((sqrtf(t2) + EPSN) * (sqrtf(s2) + EPSN) * 8.0f);
  }

  // Cooperative staging of one 64-key tile: K,T,S [key][d] bf16 + V [d][key]
  // f16, 8 KB each. 2048 slots of 16B; slot s -> tensor s>>9, row (s>>3)&63,
  // col-slot s&7. Global source pre-swizzled so LDS holds slot^(row&7).
  auto stage = [&](int kb, int pb) {
#pragma unroll
    for (int i = 0; i < 8; ++i) {
      const int s  = i * 256 + tid;
      const int r  = (s >> 3) & 63;
      const int cs = ((s & 7) ^ (r & 7)) * 8;
      unsigned short* dst = &Ls[pb][0][0][0] + s * 8;
      if (i < 2)      gld16(GT0 + base_h + (kb + r) * 64 + cs, dst);
      else if (i < 4) gld16(GT1 + base_h + (kb + r) * 64 + cs, dst);
      else if (i < 6) gld16(GT2 + base_h + (kb + r) * 64 + cs, dst);
      else            gld16(Vtu + ((size_t)(bh * 64 + r)) * 1024 + kb + cs, dst);
    }
  };

  float m_[2], l_[2];
  fx4 o[2][4];
#pragma unroll
  for (int g = 0; g < 2; ++g) {
    m_[g] = -1.0e30f; l_[g] = 0.f;
#pragma unroll
    for (int fd = 0; fd < 4; ++fd) o[g][fd] = (fx4){0.f, 0.f, 0.f, 0.f};
  }
  const fx4 zero = (fx4){0.f, 0.f, 0.f, 0.f};

  stage(0, 0);
  __syncthreads();

#pragma unroll 1
  for (int t = 0; t < 16; ++t) {
    const int pb = t & 1;
    if (t + 1 < 16) stage((t + 1) * 64, pb ^ 1);
    const int kb = t * 64;

    // ---- full 64-key tile: all 4 ff frags from LDS (swizzled reads) ----
    bf8 ak[4][2], at_[4][2], as_[4][2];
    h4 vv[4][4];
    fx4 mk[4];
#pragma unroll
    for (int f = 0; f < 4; ++f) {
      const int row = f * 16 + colid;
      const int sw  = row & 7;
#pragma unroll
      for (int fr = 0; fr < 2; ++fr) {
        const int co = ((quad + fr * 4) ^ sw) * 8;
        ak[f][fr]  = *(const bf8*)&Ls[pb][0][row][co];
        at_[f][fr] = *(const bf8*)&Ls[pb][1][row][co];
        as_[f][fr] = *(const bf8*)&Ls[pb][2][row][co];
      }
#pragma unroll
      for (int fd = 0; fd < 4; ++fd) {
        const int vr = fd * 16 + colid;
        const int vo = (((f * 2 + (quad >> 1)) ^ (vr & 7)) * 8) + (quad & 1) * 4;
        vv[f][fd] = *(const h4*)&Ls[pb][3][vr][vo];
      }
      mk[f] = *(const fx4*)(maskb + b * SEQ + kb + f * 16 + quad * 4);
    }

    // ---- per q-group: 64-key scores^T, ONE online softmax, PV ----
#pragma unroll
    for (int g = 0; g < 2; ++g) {
      float sv[4][4];
#pragma unroll
      for (int f = 0; f < 4; ++f) {
        fx4 ab = __builtin_amdgcn_mfma_f32_16x16x32_bf16(ak[f][0], bqf[g][0], zero, 0, 0, 0);
        ab = __builtin_amdgcn_mfma_f32_16x16x32_bf16(ak[f][1], bqf[g][1], ab, 0, 0, 0);
        fx4 tt = __builtin_amdgcn_mfma_f32_16x16x32_bf16(at_[f][0], btf[g][0], zero, 0, 0, 0);
        tt = __builtin_amdgcn_mfma_f32_16x16x32_bf16(at_[f][1], btf[g][1], tt, 0, 0, 0);
        fx4 ss = __builtin_amdgcn_mfma_f32_16x16x32_bf16(as_[f][0], bsf[g][0], zero, 0, 0, 0);
        ss = __builtin_amdgcn_mfma_f32_16x16x32_bf16(as_[f][1], bsf[g][1], ss, 0, 0, 0);
#pragma unroll
        for (int reg = 0; reg < 4; ++reg)
          sv[f][reg] = (ab[reg] * tt[reg]) * ss[reg] * rs[g] + mk[f][reg];
      }

      // pairwise fmax tree over 16 values (depth 4), then cross-quad.
      float p01 = fmaxf(sv[0][0], sv[0][1]), p23 = fmaxf(sv[0][2], sv[0][3]);
      float p45 = fmaxf(sv[1][0], sv[1][1]), p67 = fmaxf(sv[1][2], sv[1][3]);
      float p89 = fmaxf(sv[2][0], sv[2][1]), pab = fmaxf(sv[2][2], sv[2][3]);
      float pcd = fmaxf(sv[3][0], sv[3][1]), pef = fmaxf(sv[3][2], sv[3][3]);
      float q03 = fmaxf(p01, p23), q47 = fmaxf(p45, p67);
      float q8b = fmaxf(p89, pab), qcf = fmaxf(pcd, pef);
      float bm = fmaxf(fmaxf(q03, q47), fmaxf(q8b, qcf));
      bm = crossmax(bm);   // permlane16/32_swap: VALU butterfly

      // T13 defer-max: rescale only when the tile max exceeds the running
      // max by >8. p is then bounded by e^8 (~2981, fits f16); first tile
      // always rescales (m_ = -1e30). Wave-uniform branch, no divergence.
      // alpha is quad-uniform -> scaling the LOCAL l-partial is exact.
      if (!__all(bm <= m_[g] + 8.0f)) {
        const float mn = fmaxf(m_[g], bm);
        const float alpha = __expf(m_[g] - mn);
        l_[g] *= alpha;
        m_[g] = mn;
        float ar[4];
#pragma unroll
        for (int reg = 0; reg < 4; ++reg) ar[reg] = __shfl(alpha, quad * 4 + reg);
#pragma unroll
        for (int fd = 0; fd < 4; ++fd)
#pragma unroll
          for (int reg = 0; reg < 4; ++reg) o[g][fd][reg] *= ar[reg];
      }

      const float mloc = m_[g];
      float rsum = 0.f;
      h4 pa[4];
#pragma unroll
      for (int f = 0; f < 4; ++f)
#pragma unroll
        for (int reg = 0; reg < 4; ++reg) {
          const float p = __expf(sv[f][reg] - mloc);
          rsum += p;
          pa[f][reg] = (_Float16)p;
        }
      // Deferred-l: accumulate the LOCAL partial only; cross-quad
      // reduction happens once in the epilogue.
      l_[g] += rsum;

#pragma unroll
      for (int f = 0; f < 4; ++f)
#pragma unroll
        for (int fd = 0; fd < 4; ++fd)
          o[g][fd] = __builtin_amdgcn_mfma_f32_16x16x16f16(pa[f], vv[f][fd], o[g][fd], 0, 0, 0);
    }
    __syncthreads();
  }

  // Epilogue per group: reduce l across quads once, then out = O / l.
#pragma unroll
  for (int g = 0; g < 2; ++g) {
    float lt = l_[g];
    lt += __shfl_xor(lt, 16);
    lt += __shfl_xor(lt, 32);
    const float linv = 1.0f / lt;
    float ir[4];
#pragma unroll
    for (int reg = 0; reg < 4; ++reg) ir[reg] = __shfl(linv, quad * 4 + reg);
#pragma unroll
    for (int reg = 0; reg < 4; ++reg) {
      const int s = q0 + g * 16 + quad * 4 + reg;
#pragma unroll
      for (int fd = 0; fd < 4; ++fd)
        outb[(size_t)(b * SEQ + s) * HDIM + h * DHEAD + fd * 16 + colid] = o[g][fd][reg] * ir[reg];
    }
  }
}

extern "C" void kernel_launch(void* const* d_in, const int* in_sizes, int n_in,
                              void* d_out, int out_size, void* d_ws, size_t ws_size,
                              hipStream_t stream)
{
  (void)in_sizes; (void)n_in; (void)out_size; (void)ws_size;
  const float* hs   = (const float*)d_in[0];
  const float* te   = (const float*)d_in[1];
  const float* se   = (const float*)d_in[2];
  const float* mask = (const float*)d_in[3];
  const float* Wq   = (const float*)d_in[4];
  const float* bq   = (const float*)d_in[5];
  const float* Wk   = (const float*)d_in[6];
  const float* bk   = (const float*)d_in[7];
  const float* Wv   = (const float*)d_in[8];
  const float* bv   = (const float*)d_in[9];
  const float* Wt   = (const float*)d_in[10];
  const float* bt   = (const float*)d_in[11];
  const float* Wsp  = (const float*)d_in[12];
  const float* bsp  = (const float*)d_in[13];
  float* out = (float*)d_out;
  unsigned short* ws = (unsigned short*)d_ws;

  // ws layout (ushort units): Qb@0 Kb@1SZ Tb@2SZ Sb@3SZ Vt(f16)@4SZ
  // convert-phase: hsb@5SZ teb@6SZ seb@7SZ W[5]@8SZ+z*WSZ (dead after proj)
  convert_kernel<<<dim3(1536, 8), 256, 0, stream>>>(hs, te, se, Wq, Wk, Wv, Wt, Wsp, ws);
  proj_kernel<<<dim3(960), 256, 0, stream>>>(ws, bq, bk, bv, bt, bsp);
  attn_kernel<<<dim3(384), 256, 0, stream>>>(ws, mask, out);
}

// Round 13
// 190.780 us; speedup vs baseline: 1.3747x; 1.3747x over previous
//
#include <hip/hip_runtime.h>

#define NHEADS 12
#define SEQ    1024
#define HDIM   768
#define DHEAD  64
#define BH_TOT 48
#define EPSN   1e-6f

typedef __attribute__((ext_vector_type(8))) short    bf8;  // 8 bf16 (4 VGPRs) MFMA A/B frag
typedef __attribute__((ext_vector_type(4))) float    fx4;  // MFMA C/D frag / float4
typedef __attribute__((ext_vector_type(4))) _Float16 h4;   // 4 f16 (2 VGPRs) 16x16x16 frag
typedef __attribute__((ext_vector_type(2))) unsigned int u32x2;

#define SZT 3145728u   // 48*1024*64 elements (one head-split tensor)
#define WSZ 589824u    // 768*768 elements (one weight matrix)

__device__ __forceinline__ float bf2f(unsigned short h) {
  union { unsigned int u; float f; } v; v.u = ((unsigned int)h) << 16; return v.f;
}
__device__ __forceinline__ unsigned short f2bf(float f) {
  union { float f; unsigned int u; } v; v.f = f;
  unsigned int u = v.u;
  return (unsigned short)((u + 0x7FFFu + ((u >> 16) & 1u)) >> 16);
}

// Cross-quad max (lane ^16 then ^32) via gfx950 permlane*_swap: VALU ops
// (~4cyc) replacing ds_swizzle (~120cyc LDS-pipe latency) on the softmax
// critical path. swap(x,x) returns (a',b') with per-lane fmax(a',b') =
// max(x[lane], x[lane^K]) -- bit-identical to the __shfl_xor butterfly.
__device__ __forceinline__ float crossmax(float x) {
#if __has_builtin(__builtin_amdgcn_permlane16_swap) && __has_builtin(__builtin_amdgcn_permlane32_swap)
  u32x2 r = __builtin_amdgcn_permlane16_swap(__float_as_uint(x), __float_as_uint(x), false, false);
  x = fmaxf(__uint_as_float(r.x), __uint_as_float(r.y));
  r = __builtin_amdgcn_permlane32_swap(__float_as_uint(x), __float_as_uint(x), false, false);
  x = fmaxf(__uint_as_float(r.x), __uint_as_float(r.y));
#else
  x = fmaxf(x, __shfl_xor(x, 16));
  x = fmaxf(x, __shfl_xor(x, 32));
#endif
  return x;
}

// async global->LDS, 16B per lane; LDS dest = wave-uniform base + lane*16.
typedef __attribute__((address_space(3))) unsigned int lds_u32;
typedef __attribute__((address_space(1))) const unsigned int glb_u32;
__device__ __forceinline__ void gld16(const unsigned short* g, unsigned short* l) {
  __builtin_amdgcn_global_load_lds((glb_u32*)g, (lds_u32*)l, 16, 0, 0);
}

// ---------------------------------------------------------------------------
// One-shot f32 -> bf16 conversion of X (hs,te,se) and W (q,k,v,t,s) into ws.
// Layout (ushort units): hsb@5SZ teb@6SZ seb@7SZ  W[z]@8SZ + z*WSZ
// ---------------------------------------------------------------------------
__global__ void convert_kernel(const float* __restrict__ hs, const float* __restrict__ te,
                               const float* __restrict__ se,
                               const float* __restrict__ Wq, const float* __restrict__ Wk,
                               const float* __restrict__ Wv, const float* __restrict__ Wt,
                               const float* __restrict__ Ws2,
                               unsigned short* __restrict__ ws)
{
  const int z = blockIdx.y;
  const float* src;
  unsigned short* dst;
  int n;
  if (z < 3) {
    src = (z == 0) ? hs : (z == 1) ? te : se;
    dst = ws + (size_t)(5 + z) * SZT;
    n = 3145728;
  } else {
    src = (z == 3) ? Wq : (z == 4) ? Wk : (z == 5) ? Wv : (z == 6) ? Wt : Ws2;
    dst = ws + (size_t)8 * SZT + (size_t)(z - 3) * WSZ;
    n = 589824;
  }
  const int base = (blockIdx.x * 256 + threadIdx.x) * 8;
  if (base >= n) return;
  const fx4 a = *(const fx4*)(src + base);
  const fx4 b = *(const fx4*)(src + base + 4);
  bf8 o;
#pragma unroll
  for (int j = 0; j < 4; ++j) { o[j] = (short)f2bf(a[j]); o[4 + j] = (short)f2bf(b[j]); }
  *(bf8*)(dst + base) = o;
}

// ---------------------------------------------------------------------------
// Projection GEMM (bf16 in): out = X[4096,768] @ W[768,768]^T + b, head-split.
// XCD-aware 1-D grid 960 (r8). xcd = lin&7 owns y-tiles xcd*4..xcd*4+3 for
// ALL x and z -> same-XCD blocks share X panels (784KB, L2-resident) + W
// panels. z: 0=Q 1=K 2=V(f16, transposed Vt[bh*64+d][1024]) 3=T 4=S
// ---------------------------------------------------------------------------
__global__ __launch_bounds__(256, 3)
void proj_kernel(unsigned short* __restrict__ ws,
                 const float* __restrict__ bq, const float* __restrict__ bk,
                 const float* __restrict__ bv, const float* __restrict__ bt,
                 const float* __restrict__ bs)
{
  __shared__ unsigned short Xs[2][4096];
  __shared__ unsigned short Ys[2][4096];

  // Decode XCD-grouped tile assignment from 1-D block id.
  const int lin = blockIdx.x;          // 0..959
  const int xcd = lin & 7;
  const int idx = lin >> 3;            // 0..119
  const int xt  = idx % 6;             // N-tile
  const int t2  = idx / 6;             // 0..19
  const int yl  = t2 % 4;
  const int z   = t2 / 4;              // 0..4
  const int yt  = xcd * 4 + yl;        // M-tile, grouped per XCD

  const unsigned short* X = ws + (size_t)5 * SZT + (size_t)((z < 3) ? 0 : (z - 2)) * SZT;
  const unsigned short* W = ws + (size_t)8 * SZT + (size_t)z * WSZ;
  const float* bias = (z == 0) ? bq : (z == 1) ? bk : (z == 2) ? bv : (z == 3) ? bt : bs;
  unsigned short* out = ws + (size_t)((z < 2) ? z : (z == 2) ? 4 : (z == 3) ? 2 : 3) * SZT;

  const int tid   = threadIdx.x;
  const int lane  = tid & 63;
  const int wid   = tid >> 6;
  const int wm    = wid >> 1, wn = wid & 1;
  const int colid = lane & 15, quad = lane >> 4;
  const int m0 = yt * 128, n0 = xt * 128;

  auto stage = [&](int kt, int pb) {
#pragma unroll
    for (int i = 0; i < 2; ++i) {
      const int slot = i * 256 + tid;        // 0..511, 16B each
      const int row = slot >> 2, ch = slot & 3;
      gld16(X + (m0 + row) * HDIM + kt + ch * 8, &Xs[pb][slot * 8]);
      gld16(W + (n0 + row) * HDIM + kt + ch * 8, &Ys[pb][slot * 8]);
    }
  };

  fx4 acc[4][4];
#pragma unroll
  for (int i = 0; i < 4; ++i)
#pragma unroll
    for (int j = 0; j < 4; ++j) acc[i][j] = (fx4){0.f, 0.f, 0.f, 0.f};

  stage(0, 0);
  __syncthreads();

  for (int it = 0; it < 24; ++it) {
    const int pb = it & 1;
    if (it + 1 < 24) stage((it + 1) * 32, pb ^ 1);

    bf8 af[4], bfr[4];
#pragma unroll
    for (int i = 0; i < 4; ++i)
      af[i] = *(const bf8*)&Xs[pb][(wm * 64 + i * 16 + colid) * 32 + quad * 8];
#pragma unroll
    for (int j = 0; j < 4; ++j)
      bfr[j] = *(const bf8*)&Ys[pb][(wn * 64 + j * 16 + colid) * 32 + quad * 8];
#pragma unroll
    for (int i = 0; i < 4; ++i)
#pragma unroll
      for (int j = 0; j < 4; ++j)
        acc[i][j] = __builtin_amdgcn_mfma_f32_16x16x32_bf16(af[i], bfr[j], acc[i][j], 0, 0, 0);
    __syncthreads();
  }

  // Epilogue. C/D layout: col=lane&15, row=quad*4+reg.
  if (z != 2) {
#pragma unroll
    for (int i = 0; i < 4; ++i) {
      const int r0 = m0 + wm * 64 + i * 16 + quad * 4;
      const int bb = r0 >> 10, s0 = r0 & 1023;
#pragma unroll
      for (int j = 0; j < 4; ++j) {
        const int c = n0 + wn * 64 + j * 16 + colid;
        const int h = c >> 6, d = c & 63;
        const float bvl = bias[c];
        unsigned short* op = out + (((bb * NHEADS + h) * SEQ + s0) * DHEAD + d);
#pragma unroll
        for (int reg = 0; reg < 4; ++reg)
          op[reg * DHEAD] = f2bf(acc[i][j][reg] + bvl);
      }
    }
  } else {
    // V -> f16, transposed: Vt[(bh*64+d)*1024 + s], 4 consecutive s per 8B store.
#pragma unroll
    for (int i = 0; i < 4; ++i) {
      const int r0 = m0 + wm * 64 + i * 16 + quad * 4;
      const int bb = r0 >> 10, s0 = r0 & 1023;
#pragma unroll
      for (int j = 0; j < 4; ++j) {
        const int c = n0 + wn * 64 + j * 16 + colid;
        const int h = c >> 6, d = c & 63;
        const float bvl = bias[c];
        h4 pk;
#pragma unroll
        for (int reg = 0; reg < 4; ++reg)
          pk[reg] = (_Float16)(acc[i][j][reg] + bvl);
        *(h4*)(void*)(out + ((size_t)((bb * NHEADS + h) * DHEAD + d)) * SEQ + s0) = pk;
      }
    }
  }
}

// ---------------------------------------------------------------------------
// Flash attention. Round 19: byte-exact revert to r11 (proven best: attn
// 52.8us, e2e 191.0). r12's hh-merge spilled to scratch (FETCH +30MB,
// WRITE +26MB, attn 122us) -- the hh split is load-bearing for register
// pressure; VGPR_Count=128 was the allocator's scheduling-headroom choice,
// not spendable budget (LAW 5).
// Final proven stack: r3 structure (4 waves x 32q, K/T/S/V in 64KB dbuf LDS
// via gld16 + XOR swizzle, grid 384 XCD-grouped) + T13 defer-max (r9) +
// deferred-l (r10) + permlane crossmax (r11).
// LAWS: (1) q/wave >= 32; (2) don't buy occupancy with VGPR caps or AI;
// (3) no scheduler-fencing intrinsics in the inner loop; (4) one change per
// round; (5) reported VGPR count is not spendable headroom.
// ---------------------------------------------------------------------------
__global__ __launch_bounds__(256, 2)
void attn_kernel(const unsigned short* __restrict__ ws,
                 const float* __restrict__ maskb,
                 float* __restrict__ outb)
{
  const unsigned short* Qb  = ws;
  const unsigned short* GT0 = ws + (size_t)1 * SZT;   // K
  const unsigned short* GT1 = ws + (size_t)2 * SZT;   // T
  const unsigned short* GT2 = ws + (size_t)3 * SZT;   // S
  const unsigned short* Vtu = ws + (size_t)4 * SZT;   // V f16 transposed, as ushort

  __shared__ unsigned short Ls[2][4][64][64];  // 64 KB: [buf][K,T,S,V][row][col]

  const int tid   = threadIdx.x;
  const int lane  = tid & 63;
  const int wid   = tid >> 6;          // 0..3
  const int colid = lane & 15, quad = lane >> 4;

  // XCD swizzle: 384 blocks; lin&7 = XCD; each XCD owns 6 bh entirely.
  const int lin = blockIdx.x;
  const int xcd = lin & 7;
  const int idx = lin >> 3;            // 0..47
  const int bh  = xcd * 6 + (idx % 6);
  const int qx  = idx / 6;             // 0..7
  const int b   = bh / NHEADS, h = bh % NHEADS;
  const int q0  = qx * 128 + wid * 32;
  const int base_h = bh * SEQ * DHEAD;

  // Query-side B-frags for 2 q-groups: lane holds B[k=quad*8+j][n=colid].
  bf8 bqf[2][2], btf[2][2], bsf[2][2];
  float rs[2];
#pragma unroll
  for (int g = 0; g < 2; ++g) {
    const int row = q0 + g * 16 + colid;
    const unsigned short* qp = Qb  + base_h + row * 64 + quad * 8;
    const unsigned short* tp = GT1 + base_h + row * 64 + quad * 8;
    const unsigned short* sp = GT2 + base_h + row * 64 + quad * 8;
    bqf[g][0] = *(const bf8*)qp;  bqf[g][1] = *(const bf8*)(qp + 32);
    btf[g][0] = *(const bf8*)tp;  btf[g][1] = *(const bf8*)(tp + 32);
    bsf[g][0] = *(const bf8*)sp;  bsf[g][1] = *(const bf8*)(sp + 32);
    float t2 = 0.f, s2 = 0.f;
#pragma unroll
    for (int fr = 0; fr < 2; ++fr)
#pragma unroll
      for (int j = 0; j < 8; ++j) {
        const float tv = bf2f((unsigned short)btf[g][fr][j]);
        const float sv2 = bf2f((unsigned short)bsf[g][fr][j]);
        t2 += tv * tv; s2 += sv2 * sv2;
      }
    t2 += __shfl_xor(t2, 16); t2 += __shfl_xor(t2, 32);
    s2 += __shfl_xor(s2, 16); s2 += __shfl_xor(s2, 32);
    rs[g] = 1.0f / ((sqrtf(t2) + EPSN) * (sqrtf(s2) + EPSN) * 8.0f);
  }

  // Cooperative staging of one 64-key tile: K,T,S [key][d] bf16 + V [d][key]
  // f16, 8 KB each. 2048 slots of 16B; slot s -> tensor s>>9, row (s>>3)&63,
  // col-slot s&7. Global source pre-swizzled so LDS holds slot^(row&7).
  auto stage = [&](int kb, int pb) {
#pragma unroll
    for (int i = 0; i < 8; ++i) {
      const int s  = i * 256 + tid;
      const int r  = (s >> 3) & 63;
      const int cs = ((s & 7) ^ (r & 7)) * 8;
      unsigned short* dst = &Ls[pb][0][0][0] + s * 8;
      if (i < 2)      gld16(GT0 + base_h + (kb + r) * 64 + cs, dst);
      else if (i < 4) gld16(GT1 + base_h + (kb + r) * 64 + cs, dst);
      else if (i < 6) gld16(GT2 + base_h + (kb + r) * 64 + cs, dst);
      else            gld16(Vtu + ((size_t)(bh * 64 + r)) * 1024 + kb + cs, dst);
    }
  };

  float m_[2], l_[2];
  fx4 o[2][4];
#pragma unroll
  for (int g = 0; g < 2; ++g) {
    m_[g] = -1.0e30f; l_[g] = 0.f;
#pragma unroll
    for (int fd = 0; fd < 4; ++fd) o[g][fd] = (fx4){0.f, 0.f, 0.f, 0.f};
  }
  const fx4 zero = (fx4){0.f, 0.f, 0.f, 0.f};

  stage(0, 0);
  __syncthreads();

#pragma unroll 1
  for (int t = 0; t < 16; ++t) {
    const int pb = t & 1;
    if (t + 1 < 16) stage((t + 1) * 64, pb ^ 1);
    const int kb = t * 64;

#pragma unroll
    for (int hh = 0; hh < 2; ++hh) {
      // ---- 32-key half: frags from LDS (swizzled reads) ----
      bf8 ak[2][2], at_[2][2], as_[2][2];
      h4 vv[2][4];
      fx4 mk[2];
#pragma unroll
      for (int ff = 0; ff < 2; ++ff) {
        const int f   = hh * 2 + ff;
        const int row = f * 16 + colid;
        const int sw  = row & 7;
#pragma unroll
        for (int fr = 0; fr < 2; ++fr) {
          const int co = ((quad + fr * 4) ^ sw) * 8;
          ak[ff][fr]  = *(const bf8*)&Ls[pb][0][row][co];
          at_[ff][fr] = *(const bf8*)&Ls[pb][1][row][co];
          as_[ff][fr] = *(const bf8*)&Ls[pb][2][row][co];
        }
#pragma unroll
        for (int fd = 0; fd < 4; ++fd) {
          const int vr = fd * 16 + colid;
          const int vo = (((f * 2 + (quad >> 1)) ^ (vr & 7)) * 8) + (quad & 1) * 4;
          vv[ff][fd] = *(const h4*)&Ls[pb][3][vr][vo];
        }
        mk[ff] = *(const fx4*)(maskb + b * SEQ + kb + f * 16 + quad * 4);
      }

      // ---- per q-group: scores^T, online softmax over 32 keys, PV ----
#pragma unroll
      for (int g = 0; g < 2; ++g) {
        float sv[2][4];
#pragma unroll
        for (int ff = 0; ff < 2; ++ff) {
          fx4 ab = __builtin_amdgcn_mfma_f32_16x16x32_bf16(ak[ff][0], bqf[g][0], zero, 0, 0, 0);
          ab = __builtin_amdgcn_mfma_f32_16x16x32_bf16(ak[ff][1], bqf[g][1], ab, 0, 0, 0);
          fx4 tt = __builtin_amdgcn_mfma_f32_16x16x32_bf16(at_[ff][0], btf[g][0], zero, 0, 0, 0);
          tt = __builtin_amdgcn_mfma_f32_16x16x32_bf16(at_[ff][1], btf[g][1], tt, 0, 0, 0);
          fx4 ss = __builtin_amdgcn_mfma_f32_16x16x32_bf16(as_[ff][0], bsf[g][0], zero, 0, 0, 0);
          ss = __builtin_amdgcn_mfma_f32_16x16x32_bf16(as_[ff][1], bsf[g][1], ss, 0, 0, 0);
#pragma unroll
          for (int reg = 0; reg < 4; ++reg)
            sv[ff][reg] = (ab[reg] * tt[reg]) * ss[reg] * rs[g] + mk[ff][reg];
        }

        float bm = sv[0][0];
#pragma unroll
        for (int ff = 0; ff < 2; ++ff)
#pragma unroll
          for (int reg = 0; reg < 4; ++reg) bm = fmaxf(bm, sv[ff][reg]);
        bm = crossmax(bm);   // permlane16/32_swap: VALU, was 2x ds_swizzle

        // T13 defer-max: rescale only when the tile max exceeds the running
        // max by >8. p is then bounded by e^8 (~2981, fits f16); first tile
        // always rescales (m_ = -1e30). Wave-uniform branch, no divergence.
        // alpha is quad-uniform -> scaling the LOCAL l-partial is exact.
        if (!__all(bm <= m_[g] + 8.0f)) {
          const float mn = fmaxf(m_[g], bm);
          const float alpha = __expf(m_[g] - mn);
          l_[g] *= alpha;
          m_[g] = mn;
          float ar[4];
#pragma unroll
          for (int reg = 0; reg < 4; ++reg) ar[reg] = __shfl(alpha, quad * 4 + reg);
#pragma unroll
          for (int fd = 0; fd < 4; ++fd)
#pragma unroll
            for (int reg = 0; reg < 4; ++reg) o[g][fd][reg] *= ar[reg];
        }

        const float mloc = m_[g];
        float rsum = 0.f;
        h4 pa[2];
#pragma unroll
        for (int ff = 0; ff < 2; ++ff)
#pragma unroll
          for (int reg = 0; reg < 4; ++reg) {
            const float p = __expf(sv[ff][reg] - mloc);
            rsum += p;
            pa[ff][reg] = (_Float16)p;
          }
        // Deferred-l: accumulate the LOCAL partial only; cross-quad
        // reduction happens once in the epilogue (saves 128 shfl/thread).
        l_[g] += rsum;

#pragma unroll
        for (int ff = 0; ff < 2; ++ff)
#pragma unroll
          for (int fd = 0; fd < 4; ++fd)
            o[g][fd] = __builtin_amdgcn_mfma_f32_16x16x16f16(pa[ff], vv[ff][fd], o[g][fd], 0, 0, 0);
      }
    }
    __syncthreads();
  }

  // Epilogue per group: reduce l across quads once, then out = O / l.
#pragma unroll
  for (int g = 0; g < 2; ++g) {
    float lt = l_[g];
    lt += __shfl_xor(lt, 16);
    lt += __shfl_xor(lt, 32);
    const float linv = 1.0f / lt;
    float ir[4];
#pragma unroll
    for (int reg = 0; reg < 4; ++reg) ir[reg] = __shfl(linv, quad * 4 + reg);
#pragma unroll
    for (int reg = 0; reg < 4; ++reg) {
      const int s = q0 + g * 16 + quad * 4 + reg;
#pragma unroll
      for (int fd = 0; fd < 4; ++fd)
        outb[(size_t)(b * SEQ + s) * HDIM + h * DHEAD + fd * 16 + colid] = o[g][fd][reg] * ir[reg];
    }
  }
}

extern "C" void kernel_launch(void* const* d_in, const int* in_sizes, int n_in,
                              void* d_out, int out_size, void* d_ws, size_t ws_size,
                              hipStream_t stream)
{
  (void)in_sizes; (void)n_in; (void)out_size; (void)ws_size;
  const float* hs   = (const float*)d_in[0];
  const float* te   = (const float*)d_in[1];
  const float* se   = (const float*)d_in[2];
  const float* mask = (const float*)d_in[3];
  const float* Wq   = (const float*)d_in[4];
  const float* bq   = (const float*)d_in[5];
  const float* Wk   = (const float*)d_in[6];
  const float* bk   = (const float*)d_in[7];
  const float* Wv   = (const float*)d_in[8];
  const float* bv   = (const float*)d_in[9];
  const float* Wt   = (const float*)d_in[10];
  const float* bt   = (const float*)d_in[11];
  const float* Wsp  = (const float*)d_in[12];
  const float* bsp  = (const float*)d_in[13];
  float* out = (float*)d_out;
  unsigned short* ws = (unsigned short*)d_ws;

  // ws layout (ushort units): Qb@0 Kb@1SZ Tb@2SZ Sb@3SZ Vt(f16)@4SZ
  // convert-phase: hsb@5SZ teb@6SZ seb@7SZ W[5]@8SZ+z*WSZ (dead after proj)
  convert_kernel<<<dim3(1536, 8), 256, 0, stream>>>(hs, te, se, Wq, Wk, Wv, Wt, Wsp, ws);
  proj_kernel<<<dim3(960), 256, 0, stream>>>(ws, bq, bk, bv, bt, bsp);
  attn_kernel<<<dim3(384), 256, 0, stream>>>(ws, mask, out);
}